// Round 8
// baseline (266.685 us; speedup 1.0000x reference)
//
#include <hip/hip_runtime.h>

typedef __bf16 bfrag __attribute__((ext_vector_type(8)));
typedef __bf16 bh4 __attribute__((ext_vector_type(4)));
typedef float f4 __attribute__((ext_vector_type(4)));

#define AS1C(p) (const __attribute__((address_space(1))) void*)(p)
#define AS3(p)  (__attribute__((address_space(3))) void*)(p)

// 0.125 (=1/sqrt(64)) * log2(e): folded into Q so softmax is a bare exp2
#define QSCALE 0.18033688011112042f

__device__ __forceinline__ void g2l16(const __bf16* g, __bf16* l) {
  __builtin_amdgcn_global_load_lds(AS1C(g), AS3(l), 16, 0, 0);
}

// ---------- f32 -> bf16 bulk convert: x + 4 weights in one dispatch ----------
__global__ __launch_bounds__(256) void cvt5(
    const float* __restrict__ s0, const float* __restrict__ s1,
    const float* __restrict__ s2, const float* __restrict__ s3,
    const float* __restrict__ s4,
    __bf16* __restrict__ d0, __bf16* __restrict__ d1, __bf16* __restrict__ d2,
    __bf16* __restrict__ d3, __bf16* __restrict__ d4, long n0, long n1) {
  const float* s; __bf16* d; long n;
  switch (blockIdx.y) {
    case 0: s = s0; d = d0; n = n0; break;
    case 1: s = s1; d = d1; n = n1; break;
    case 2: s = s2; d = d2; n = n1; break;
    case 3: s = s3; d = d3; n = n1; break;
    default: s = s4; d = d4; n = n1; break;
  }
  long i = ((long)blockIdx.x * 256 + threadIdx.x) * 8;
  if (i >= n) return;
  float4 a = *(const float4*)(s + i);
  float4 b = *(const float4*)(s + i + 4);
  bfrag o;
  o[0] = (__bf16)a.x; o[1] = (__bf16)a.y; o[2] = (__bf16)a.z; o[3] = (__bf16)a.w;
  o[4] = (__bf16)b.x; o[5] = (__bf16)b.y; o[6] = (__bf16)b.z; o[7] = (__bf16)b.w;
  *(bfrag*)(d + i) = o;
}

#define BARR __builtin_amdgcn_s_barrier()
#define WAIT_LGKM { asm volatile("s_waitcnt lgkmcnt(0)" ::: "memory"); \
                    __builtin_amdgcn_sched_barrier(0); }
#define WAIT_VM(N) asm volatile("s_waitcnt vmcnt(" #N ")" ::: "memory")

// ============ deep-pipeline GEMM: 128x256 tile, TRIPLE-buffered BK=64 ======
// Best measured GEMM variant (r3: 65.4us). Stage tile t+2 while computing
// tile t; vmcnt(6); 2 barriers per 2 K-tiles; T2 swizzle.
template <int MODE>  // 0: QKV epilogue (by bn), 1: f32 C store (projection)
__global__ __launch_bounds__(512, 2) void gemm_dp(
    const __bf16* __restrict__ A, const __bf16* __restrict__ Bw,
    __bf16* __restrict__ qb, __bf16* __restrict__ kb,
    __bf16* __restrict__ vt, float* __restrict__ Cf, int K) {
  __shared__ __bf16 lds[73728];          // A: 3x8192 | B: 3x16384 (144 KiB)
  __bf16* ldsA = lds;
  __bf16* ldsB = lds + 24576;
  const int tid = threadIdx.x;
  const int wave = tid >> 6, lane = tid & 63;
  const int lm = lane & 15, quad = lane >> 4;
  const int wm = wave >> 2, wn = wave & 3;   // 2m x 4n waves, 64x64 each
  const int bm = blockIdx.x * 128, bn = blockIdx.y * 256;
  const int srow = lane >> 3;                // staging row-within-16
  const int scol = ((lane & 7) ^ srow) * 8;  // pre-swizzled source col
  const int rsw = lm & 7;                    // read-side swizzle key

#define STG_A9(sl, kt) { \
    const __bf16* gp_ = A + (long)(bm + wave * 16 + srow) * K + (kt) * 64 + scol; \
    __bf16* lp_ = ldsA + (sl) * 8192 + wave * 1024 + lane * 8; \
    g2l16(gp_, lp_); g2l16(gp_ + 8 * K, lp_ + 512); }
#define STG_B9(sl, kt, h) { \
    const __bf16* gp_ = Bw + (long)(bn + (h) * 128 + wave * 16 + srow) * K + (kt) * 64 + scol; \
    __bf16* lp_ = ldsB + (sl) * 16384 + (h) * 8192 + wave * 1024 + lane * 8; \
    g2l16(gp_, lp_); g2l16(gp_ + 8 * K, lp_ + 512); }
#define STG_TILE(sl, kt) { STG_A9(sl, kt); STG_B9(sl, kt, 0); STG_B9(sl, kt, 1); }

#define COMPUTE_HALF(sl) { \
    const __bf16* Ab_ = ldsA + (sl) * 8192 + (wm * 64 + lm) * 64; \
    const __bf16* Bb_ = ldsB + (sl) * 16384 + (wn * 64 + lm) * 64; \
    bfrag af_[4][2], bg_[2][2]; \
    _Pragma("unroll") for (int j_ = 0; j_ < 4; ++j_) \
      _Pragma("unroll") for (int kk_ = 0; kk_ < 2; ++kk_) \
        af_[j_][kk_] = *(const bfrag*)(Ab_ + j_ * 1024 + ((kk_ * 4 + quad) ^ rsw) * 8); \
    _Pragma("unroll") for (int n_ = 0; n_ < 2; ++n_) \
      _Pragma("unroll") for (int kk_ = 0; kk_ < 2; ++kk_) \
        bg_[n_][kk_] = *(const bfrag*)(Bb_ + n_ * 1024 + ((kk_ * 4 + quad) ^ rsw) * 8); \
    WAIT_LGKM; \
    __builtin_amdgcn_s_setprio(1); \
    _Pragma("unroll") for (int j_ = 0; j_ < 4; ++j_) \
      _Pragma("unroll") for (int n_ = 0; n_ < 2; ++n_) \
        _Pragma("unroll") for (int kk_ = 0; kk_ < 2; ++kk_) \
          acc[j_][n_] = __builtin_amdgcn_mfma_f32_16x16x32_bf16( \
              af_[j_][kk_], bg_[n_][kk_], acc[j_][n_], 0, 0, 0); \
    __builtin_amdgcn_s_setprio(0); \
    _Pragma("unroll") for (int n_ = 0; n_ < 2; ++n_) \
      _Pragma("unroll") for (int kk_ = 0; kk_ < 2; ++kk_) \
        bg_[n_][kk_] = *(const bfrag*)(Bb_ + (2 + n_) * 1024 + ((kk_ * 4 + quad) ^ rsw) * 8); \
    WAIT_LGKM; \
    __builtin_amdgcn_s_setprio(1); \
    _Pragma("unroll") for (int j_ = 0; j_ < 4; ++j_) \
      _Pragma("unroll") for (int n_ = 0; n_ < 2; ++n_) \
        _Pragma("unroll") for (int kk_ = 0; kk_ < 2; ++kk_) \
          acc[j_][2 + n_] = __builtin_amdgcn_mfma_f32_16x16x32_bf16( \
              af_[j_][kk_], bg_[n_][kk_], acc[j_][2 + n_], 0, 0, 0); \
    __builtin_amdgcn_s_setprio(0); }

  f4 acc[4][4] = {};
  const int ntiles = K >> 6;           // 16
  STG_TILE(0, 0);
  STG_TILE(1, 1);
  WAIT_VM(6);
  BARR;
#pragma unroll 1
  for (int i = 0; i < (ntiles >> 1); ++i) {
    const int e = 2 * i, o = 2 * i + 1;
    const int se = e % 3, so = o % 3;
    if (e + 2 < ntiles) { const int s2 = (e + 2) % 3; STG_TILE(s2, e + 2); }
    COMPUTE_HALF(se);
    if (e + 2 < ntiles) { WAIT_VM(6); } else { WAIT_VM(0); }
    BARR;
    if (o + 2 < ntiles) { const int s2 = (o + 2) % 3; STG_TILE(s2, o + 2); }
    COMPUTE_HALF(so);
    if (o + 2 < ntiles) WAIT_VM(6);
    BARR;
  }

  if (MODE == 1) {
#pragma unroll
    for (int mi = 0; mi < 4; ++mi)
#pragma unroll
      for (int ni = 0; ni < 4; ++ni)
#pragma unroll
        for (int r = 0; r < 4; ++r) {
          long row = bm + wm * 64 + mi * 16 + quad * 4 + r;
          long col = bn + wn * 64 + ni * 16 + lm;
          Cf[row * 1024 + col] = acc[mi][ni][r];
        }
  } else if (bn < 2048) {
    __bf16* dst = (bn < 1024) ? qb : kb;
    const float scl = (bn < 1024) ? QSCALE : 1.0f;
    const int nb = bn & 1023;
#pragma unroll
    for (int mi = 0; mi < 4; ++mi)
#pragma unroll
      for (int ni = 0; ni < 4; ++ni)
#pragma unroll
        for (int r = 0; r < 4; ++r) {
          long row = bm + wm * 64 + mi * 16 + quad * 4 + r;
          long col = nb + wn * 64 + ni * 16 + lm;
          dst[row * 1024 + col] = (__bf16)(acc[mi][ni][r] * scl);
        }
  } else {
#pragma unroll
    for (int mi = 0; mi < 4; ++mi)
#pragma unroll
      for (int ni = 0; ni < 4; ++ni)
#pragma unroll
        for (int r = 0; r < 4; ++r) {
          int d = wn * 64 + ni * 16 + lm;
          int tp = wm * 64 + (quad * 4 + r) * 4 + mi;
          lds[d * 130 + tp] = (__bf16)acc[mi][ni][r];
        }
    __syncthreads();
    const int bloc = bm >> 11;
    const int tloc = bm & 2047;
#pragma unroll
    for (int p = 0; p < 8; ++p) {
      int d = (tid >> 4) + p * 32;
      int c = (tid & 15) * 8;
      long dglob = (bn - 2048) + d;
      *(bfrag*)(vt + ((long)bloc * 1024 + dglob) * 2048 + tloc + c) =
          *(const bfrag*)(lds + d * 130 + c);
    }
  }
}

// ---------- fallback GEMM (f32 A / f32 B, inline convert) ----------
template <bool A_F32, bool OUT_F32>
__global__ __launch_bounds__(256) void gemm_bt_cv(
    const void* __restrict__ Ap, const float* __restrict__ Bp,
    void* __restrict__ Cp, int M, int N, int K, float scl) {
  __shared__ __bf16 As[128 * 32];
  __shared__ __bf16 Bs[128 * 32];
  const int tid = threadIdx.x;
  const int lane = tid & 63, wave = tid >> 6;
  const int lm = lane & 15, quad = lane >> 4;
  const int bm = blockIdx.x * 128, bn = blockIdx.y * 128;
  const int wr = (wave >> 1) * 64, wc = (wave & 1) * 64;
  const int e0 = tid * 16, sr = e0 >> 5, sc = e0 & 31;
  f4 acc[4][4] = {};
  for (int k0 = 0; k0 < K; k0 += 32) {
    if (A_F32) {
      const float4* ga = (const float4*)((const float*)Ap + (long)(bm + sr) * K + k0 + sc);
#pragma unroll
      for (int j = 0; j < 4; ++j) {
        float4 v = ga[j];
        As[sr * 32 + sc + j * 4 + 0] = (__bf16)v.x;
        As[sr * 32 + sc + j * 4 + 1] = (__bf16)v.y;
        As[sr * 32 + sc + j * 4 + 2] = (__bf16)v.z;
        As[sr * 32 + sc + j * 4 + 3] = (__bf16)v.w;
      }
    } else {
      const __bf16* Ab = (const __bf16*)Ap + (long)(bm + sr) * K + k0 + sc;
      *(bfrag*)(As + sr * 32 + sc) = *(const bfrag*)Ab;
      *(bfrag*)(As + sr * 32 + sc + 8) = *(const bfrag*)(Ab + 8);
    }
    {
      const float4* gb = (const float4*)(Bp + (long)(bn + sr) * K + k0 + sc);
#pragma unroll
      for (int j = 0; j < 4; ++j) {
        float4 v = gb[j];
        Bs[sr * 32 + sc + j * 4 + 0] = (__bf16)v.x;
        Bs[sr * 32 + sc + j * 4 + 1] = (__bf16)v.y;
        Bs[sr * 32 + sc + j * 4 + 2] = (__bf16)v.z;
        Bs[sr * 32 + sc + j * 4 + 3] = (__bf16)v.w;
      }
    }
    __syncthreads();
    bfrag af[4], bg[4];
#pragma unroll
    for (int mi = 0; mi < 4; ++mi)
      af[mi] = *(const bfrag*)(As + (wr + mi * 16 + lm) * 32 + quad * 8);
#pragma unroll
    for (int ni = 0; ni < 4; ++ni)
      bg[ni] = *(const bfrag*)(Bs + (wc + ni * 16 + lm) * 32 + quad * 8);
#pragma unroll
    for (int mi = 0; mi < 4; ++mi)
#pragma unroll
      for (int ni = 0; ni < 4; ++ni)
        acc[mi][ni] = __builtin_amdgcn_mfma_f32_16x16x32_bf16(af[mi], bg[ni], acc[mi][ni], 0, 0, 0);
    __syncthreads();
  }
#pragma unroll
  for (int mi = 0; mi < 4; ++mi)
#pragma unroll
    for (int ni = 0; ni < 4; ++ni)
#pragma unroll
      for (int r = 0; r < 4; ++r) {
        long row = bm + wr + mi * 16 + quad * 4 + r;
        long col = bn + wc + ni * 16 + lm;
        if (OUT_F32) ((float*)Cp)[row * N + col] = acc[mi][ni][r] * scl;
        else ((__bf16*)Cp)[row * N + col] = (__bf16)(acc[mi][ni][r] * scl);
      }
}

// ---------- flash attention v11: fragment software pipeline ----------
// v10 addressing kept byte-identical (swizzled Ks/Vs/P, proven). Changes:
// (1) P double-buffered by fragment parity (2x2KB/wave, LDS 49KB->32KB);
// (2) vf loaded early (retires under QK); (3) per-fragment pipeline:
// QK(fr+1)'s 8 MFMAs sit between P-write(fr) and the lgkm drain, so the
// drain + pf-read latency hides under matrix work instead of sitting on
// the serial chain (kernel is latency-bound: 2 waves/SIMD, both pipes
// <50%). WAR on P buffers is same-wave in-order DS + program order.
template <bool VT>
__global__ __launch_bounds__(256, 2) void attn_fwd11(
    const __bf16* Qg, const __bf16* __restrict__ Kg,
    const __bf16* __restrict__ Vsrc, __bf16* Yg) {
  const int TT = 2048, CC = 1024;
  __shared__ __bf16 Ks[64 * 64];        // 8 KB, swizzled
  __shared__ __bf16 Vs[64 * 64];        // 8 KB, swizzled (V^T kappa')
  __shared__ __bf16 Ps[4 * 2 * 1024];   // 16 KB: per-wave 2 P buffers
  const int tid = threadIdx.x;
  const int wave = tid >> 6, lane = tid & 63;
  const int lm = lane & 15, quad = lane >> 4;
  const int bh = blockIdx.x, i = blockIdx.y;
  const int b = bh >> 4, h = bh & 15;
  const int qtA = i, qtB = 15 - i;
  const long rbase = (long)b * TT;
  const int hoff = h * 64;
  int row0[4];
  row0[0] = qtA * 128 + wave * 16;
  row0[1] = qtA * 128 + 64 + wave * 16;
  row0[2] = qtB * 128 + wave * 16;
  row0[3] = qtB * 128 + 64 + wave * 16;
  __bf16* Pb0 = Ps + wave * 2048;
  __bf16* Pb1 = Pb0 + 1024;
  bfrag qf[4][2];
#pragma unroll
  for (int fr = 0; fr < 4; ++fr)
#pragma unroll
    for (int f = 0; f < 2; ++f)
      qf[fr][f] = *(const bfrag*)(Qg + (rbase + row0[fr] + lm) * CC + hoff + f * 32 + quad * 8);
  bfrag ones;
#pragma unroll
  for (int j = 0; j < 8; ++j) ones[j] = (__bf16)1.0f;
  f4 y[4][4] = {};
  f4 L[4] = {};

  const int psl = ((tid & 7) ^ ((tid >> 3) & 7)) * 8;
  const int rsw = lm & 7;

#define QKF(fr, dst) { \
    _Pragma("unroll") for (int sub = 0; sub < 4; ++sub) { \
      f4 z_ = {}; \
      _Pragma("unroll") for (int f = 0; f < 2; ++f) \
        z_ = __builtin_amdgcn_mfma_f32_16x16x32_bf16(qf[fr][f], kf[sub * 2 + f], z_, 0, 0, 0); \
      dst[sub] = z_; } }

#define EXPW(fr, src) { \
    __bf16* Pw_ = ((fr) & 1) ? Pb1 : Pb0; \
    if (kBase + 63 > row0[fr]) { \
      _Pragma("unroll") for (int r = 0; r < 4; ++r) { \
        int prow_ = quad * 4 + r; bh4 pk_; \
        _Pragma("unroll") for (int sub = 0; sub < 4; ++sub) { \
          float pv_ = __builtin_amdgcn_exp2f(src[sub][r]); \
          bool m_ = (kBase + sub * 16 + lm > row0[fr] + prow_); \
          pk_[sub] = (__bf16)(m_ ? 0.f : pv_); } \
        *(bh4*)(Pw_ + prow_ * 64 + ((lm >> 1) ^ (prow_ & 7)) * 8 + (lm & 1) * 4) = pk_; } \
    } else { \
      _Pragma("unroll") for (int r = 0; r < 4; ++r) { \
        int prow_ = quad * 4 + r; bh4 pk_; \
        _Pragma("unroll") for (int sub = 0; sub < 4; ++sub) \
          pk_[sub] = (__bf16)__builtin_amdgcn_exp2f(src[sub][r]); \
        *(bh4*)(Pw_ + prow_ * 64 + ((lm >> 1) ^ (prow_ & 7)) * 8 + (lm & 1) * 4) = pk_; } } }

#define PVF(fr) { \
    const __bf16* Pw_ = ((fr) & 1) ? Pb1 : Pb0; \
    _Pragma("unroll") for (int f = 0; f < 2; ++f) { \
      bfrag pf_ = *(const bfrag*)(Pw_ + lm * 64 + ((f * 4 + quad) ^ rsw) * 8); \
      L[fr] = __builtin_amdgcn_mfma_f32_16x16x32_bf16(pf_, ones, L[fr], 0, 0, 0); \
      _Pragma("unroll") for (int ds = 0; ds < 4; ++ds) \
        y[fr][ds] = __builtin_amdgcn_mfma_f32_16x16x32_bf16(pf_, vf[ds * 2 + f], y[fr][ds], 0, 0, 0); } }

  const int ktLast = 2 * qtB + 1;
  bfrag kin[2], vin[2];
#pragma unroll
  for (int s = 0; s < 2; ++s) {
    int idx = tid + s * 256;
    int r = idx >> 3, c = (idx & 7) * 8;
    kin[s] = *(const bfrag*)(Kg + (rbase + r) * CC + hoff + c);
    if (VT)
      vin[s] = *(const bfrag*)(Vsrc + ((long)b * 1024 + hoff + r) * 2048 + c);
    else
      vin[s] = *(const bfrag*)(Vsrc + (rbase + r) * CC + hoff + c);
  }

  for (int kt = 0; kt <= ktLast; ++kt) {
    const int kBase = kt * 64;
    __syncthreads();
#pragma unroll
    for (int s = 0; s < 2; ++s) {
      int idx = tid + s * 256;
      int r = idx >> 3, c = (idx & 7) * 8;
      *(bfrag*)(Ks + r * 64 + psl) = kin[s];
      if (VT) {
        *(bfrag*)(Vs + r * 64 + psl) = vin[s];
      } else {
        int kp = (r & 15) * 4 + (r >> 4);
#pragma unroll
        for (int j = 0; j < 8; ++j)
          Vs[(c + j) * 64 + ((kp >> 3) ^ ((c + j) & 7)) * 8 + (kp & 7)] = vin[s][j];
      }
    }
    const bool more = (kt < ktLast);
    bfrag kin2[2], vin2[2];
    if (more) {
      const int nB = kBase + 64;
#pragma unroll
      for (int s = 0; s < 2; ++s) {
        int idx = tid + s * 256;
        int r = idx >> 3, c = (idx & 7) * 8;
        kin2[s] = *(const bfrag*)(Kg + (rbase + nB + r) * CC + hoff + c);
        if (VT)
          vin2[s] = *(const bfrag*)(Vsrc + ((long)b * 1024 + hoff + r) * 2048 + nB + c);
        else
          vin2[s] = *(const bfrag*)(Vsrc + (rbase + nB + r) * CC + hoff + c);
      }
    }
    __syncthreads();
    // K and V fragments both loaded early; vf retires under QK MFMAs
    bfrag kf[8], vf[8];
#pragma unroll
    for (int sub = 0; sub < 4; ++sub)
#pragma unroll
      for (int f = 0; f < 2; ++f) {
        kf[sub * 2 + f] = *(const bfrag*)(Ks + (sub * 16 + lm) * 64 + ((f * 4 + quad) ^ rsw) * 8);
        vf[sub * 2 + f] = *(const bfrag*)(Vs + (sub * 16 + lm) * 64 + ((f * 4 + quad) ^ rsw) * 8);
      }
    // prologue: QK for the first active fragment (active set is a suffix)
    f4 sc[4];
    if (kBase <= row0[0] + 15)      { QKF(0, sc); }
    else if (kBase <= row0[1] + 15) { QKF(1, sc); }
    else if (kBase <= row0[2] + 15) { QKF(2, sc); }
    else                            { QKF(3, sc); }
    // pipelined fragment loop: QK(fr+1) hides P-write(fr) drain
#pragma unroll
    for (int fr = 0; fr < 4; ++fr) {
      if (kBase <= row0[fr] + 15) {
        EXPW(fr, sc);
        if (fr < 3) {
          f4 nsc[4];
          QKF(fr + 1, nsc);
          WAIT_LGKM;
          PVF(fr);
#pragma unroll
          for (int s2 = 0; s2 < 4; ++s2) sc[s2] = nsc[s2];
        } else {
          WAIT_LGKM;
          PVF(fr);
        }
      }
    }
    if (more) {
      kin[0] = kin2[0]; kin[1] = kin2[1];
      vin[0] = vin2[0]; vin[1] = vin2[1];
    }
  }
#pragma unroll
  for (int fr = 0; fr < 4; ++fr)
#pragma unroll
    for (int ds = 0; ds < 4; ++ds)
#pragma unroll
      for (int r = 0; r < 4; ++r) {
        long row = rbase + row0[fr] + quad * 4 + r;
        Yg[row * CC + hoff + ds * 16 + lm] = (__bf16)(y[fr][ds][r] / L[fr][r]);
      }
#undef QKF
#undef EXPW
#undef PVF
}

extern "C" void kernel_launch(void* const* d_in, const int* in_sizes, int n_in,
                              void* d_out, int out_size, void* d_ws, size_t ws_size,
                              hipStream_t stream) {
  (void)in_sizes; (void)n_in; (void)out_size;
  const float* x  = (const float*)d_in[0];
  const float* Wq = (const float*)d_in[1];
  const float* Wk = (const float*)d_in[2];
  const float* Wv = (const float*)d_in[3];
  const float* Wp = (const float*)d_in[4];
  float* out = (float*)d_out;
  const long R = 8192;             // B*T
  const long BUF = R * 1024;
  const long WN = 1024L * 1024;
  __bf16* qb = (__bf16*)d_ws;      // q (pre-scaled), then y in-place
  __bf16* kb = (__bf16*)d_out;     // k + vt borrow d_out (dead before final GEMM)
  __bf16* vslot = kb + BUF;
  dim3 blk(256, 1, 1);
  const size_t need = (size_t)(2 * BUF + 4 * WN) * 2;
  if (ws_size >= need) {
    __bf16* xb = qb + BUF;
    __bf16* wqkv = xb + BUF;       // Wq,Wk,Wv contiguous = [3072][1024]
    __bf16* wpb = wqkv + 3 * WN;
    cvt5<<<dim3((unsigned)(BUF / (256 * 8)), 5, 1), blk, 0, stream>>>(
        x, Wq, Wk, Wv, Wp, xb, wqkv, wqkv + WN, wqkv + 2 * WN, wpb, BUF, WN);
    gemm_dp<0><<<dim3(64, 12, 1), dim3(512, 1, 1), 0, stream>>>(
        xb, wqkv, qb, kb, vslot, nullptr, 1024);
    attn_fwd11<true><<<dim3(64, 8, 1), blk, 0, stream>>>(qb, kb, vslot, qb);
    gemm_dp<1><<<dim3(64, 4, 1), dim3(512, 1, 1), 0, stream>>>(
        qb, wpb, nullptr, nullptr, nullptr, out, 1024);
  } else {
    gemm_bt_cv<true, false><<<dim3(64, 8, 1), blk, 0, stream>>>(x, Wq, qb, 8192, 1024, 1024, QSCALE);
    gemm_bt_cv<true, false><<<dim3(64, 8, 1), blk, 0, stream>>>(x, Wk, kb, 8192, 1024, 1024, 1.0f);
    gemm_bt_cv<true, false><<<dim3(64, 8, 1), blk, 0, stream>>>(x, Wv, vslot, 8192, 1024, 1024, 1.0f);
    attn_fwd11<false><<<dim3(64, 8, 1), blk, 0, stream>>>(qb, kb, vslot, qb);
    gemm_bt_cv<false, true><<<dim3(64, 8, 1), blk, 0, stream>>>(qb, Wp, out, 8192, 1024, 1024, 1.0f);
  }
}

// Round 9
// 233.328 us; speedup vs baseline: 1.1430x; 1.1430x over previous
//
#include <hip/hip_runtime.h>

typedef __bf16 bfrag __attribute__((ext_vector_type(8)));
typedef __bf16 bh4 __attribute__((ext_vector_type(4)));
typedef float f4 __attribute__((ext_vector_type(4)));

#define AS1C(p) (const __attribute__((address_space(1))) void*)(p)
#define AS3(p)  (__attribute__((address_space(3))) void*)(p)

// 0.125 (=1/sqrt(64)) * log2(e): folded into Q so softmax is a bare exp2
#define QSCALE 0.18033688011112042f

__device__ __forceinline__ void g2l16(const __bf16* g, __bf16* l) {
  __builtin_amdgcn_global_load_lds(AS1C(g), AS3(l), 16, 0, 0);
}

// ---------- f32 -> bf16 bulk convert: x + 4 weights in one dispatch ----------
__global__ __launch_bounds__(256) void cvt5(
    const float* __restrict__ s0, const float* __restrict__ s1,
    const float* __restrict__ s2, const float* __restrict__ s3,
    const float* __restrict__ s4,
    __bf16* __restrict__ d0, __bf16* __restrict__ d1, __bf16* __restrict__ d2,
    __bf16* __restrict__ d3, __bf16* __restrict__ d4, long n0, long n1) {
  const float* s; __bf16* d; long n;
  switch (blockIdx.y) {
    case 0: s = s0; d = d0; n = n0; break;
    case 1: s = s1; d = d1; n = n1; break;
    case 2: s = s2; d = d2; n = n1; break;
    case 3: s = s3; d = d3; n = n1; break;
    default: s = s4; d = d4; n = n1; break;
  }
  long i = ((long)blockIdx.x * 256 + threadIdx.x) * 8;
  if (i >= n) return;
  float4 a = *(const float4*)(s + i);
  float4 b = *(const float4*)(s + i + 4);
  bfrag o;
  o[0] = (__bf16)a.x; o[1] = (__bf16)a.y; o[2] = (__bf16)a.z; o[3] = (__bf16)a.w;
  o[4] = (__bf16)b.x; o[5] = (__bf16)b.y; o[6] = (__bf16)b.z; o[7] = (__bf16)b.w;
  *(bfrag*)(d + i) = o;
}

#define BARR __builtin_amdgcn_s_barrier()
#define WAIT_LGKM { asm volatile("s_waitcnt lgkmcnt(0)" ::: "memory"); \
                    __builtin_amdgcn_sched_barrier(0); }
#define WAIT_VM(N) asm volatile("s_waitcnt vmcnt(" #N ")" ::: "memory")

// ============ deep-pipeline GEMM: 128x256 tile, TRIPLE-buffered BK=64 ======
// Best measured GEMM variant (r3: 65.4us). Stage tile t+2 while computing
// tile t; vmcnt(6); 2 barriers per 2 K-tiles; T2 swizzle.
template <int MODE>  // 0: QKV epilogue (by bn), 1: f32 C store (projection)
__global__ __launch_bounds__(512, 2) void gemm_dp(
    const __bf16* __restrict__ A, const __bf16* __restrict__ Bw,
    __bf16* __restrict__ qb, __bf16* __restrict__ kb,
    __bf16* __restrict__ vt, float* __restrict__ Cf, int K) {
  __shared__ __bf16 lds[73728];          // A: 3x8192 | B: 3x16384 (144 KiB)
  __bf16* ldsA = lds;
  __bf16* ldsB = lds + 24576;
  const int tid = threadIdx.x;
  const int wave = tid >> 6, lane = tid & 63;
  const int lm = lane & 15, quad = lane >> 4;
  const int wm = wave >> 2, wn = wave & 3;   // 2m x 4n waves, 64x64 each
  const int bm = blockIdx.x * 128, bn = blockIdx.y * 256;
  const int srow = lane >> 3;                // staging row-within-16
  const int scol = ((lane & 7) ^ srow) * 8;  // pre-swizzled source col
  const int rsw = lm & 7;                    // read-side swizzle key

#define STG_A9(sl, kt) { \
    const __bf16* gp_ = A + (long)(bm + wave * 16 + srow) * K + (kt) * 64 + scol; \
    __bf16* lp_ = ldsA + (sl) * 8192 + wave * 1024 + lane * 8; \
    g2l16(gp_, lp_); g2l16(gp_ + 8 * K, lp_ + 512); }
#define STG_B9(sl, kt, h) { \
    const __bf16* gp_ = Bw + (long)(bn + (h) * 128 + wave * 16 + srow) * K + (kt) * 64 + scol; \
    __bf16* lp_ = ldsB + (sl) * 16384 + (h) * 8192 + wave * 1024 + lane * 8; \
    g2l16(gp_, lp_); g2l16(gp_ + 8 * K, lp_ + 512); }
#define STG_TILE(sl, kt) { STG_A9(sl, kt); STG_B9(sl, kt, 0); STG_B9(sl, kt, 1); }

#define COMPUTE_HALF(sl) { \
    const __bf16* Ab_ = ldsA + (sl) * 8192 + (wm * 64 + lm) * 64; \
    const __bf16* Bb_ = ldsB + (sl) * 16384 + (wn * 64 + lm) * 64; \
    bfrag af_[4][2], bg_[2][2]; \
    _Pragma("unroll") for (int j_ = 0; j_ < 4; ++j_) \
      _Pragma("unroll") for (int kk_ = 0; kk_ < 2; ++kk_) \
        af_[j_][kk_] = *(const bfrag*)(Ab_ + j_ * 1024 + ((kk_ * 4 + quad) ^ rsw) * 8); \
    _Pragma("unroll") for (int n_ = 0; n_ < 2; ++n_) \
      _Pragma("unroll") for (int kk_ = 0; kk_ < 2; ++kk_) \
        bg_[n_][kk_] = *(const bfrag*)(Bb_ + n_ * 1024 + ((kk_ * 4 + quad) ^ rsw) * 8); \
    WAIT_LGKM; \
    __builtin_amdgcn_s_setprio(1); \
    _Pragma("unroll") for (int j_ = 0; j_ < 4; ++j_) \
      _Pragma("unroll") for (int n_ = 0; n_ < 2; ++n_) \
        _Pragma("unroll") for (int kk_ = 0; kk_ < 2; ++kk_) \
          acc[j_][n_] = __builtin_amdgcn_mfma_f32_16x16x32_bf16( \
              af_[j_][kk_], bg_[n_][kk_], acc[j_][n_], 0, 0, 0); \
    __builtin_amdgcn_s_setprio(0); \
    _Pragma("unroll") for (int n_ = 0; n_ < 2; ++n_) \
      _Pragma("unroll") for (int kk_ = 0; kk_ < 2; ++kk_) \
        bg_[n_][kk_] = *(const bfrag*)(Bb_ + (2 + n_) * 1024 + ((kk_ * 4 + quad) ^ rsw) * 8); \
    WAIT_LGKM; \
    __builtin_amdgcn_s_setprio(1); \
    _Pragma("unroll") for (int j_ = 0; j_ < 4; ++j_) \
      _Pragma("unroll") for (int n_ = 0; n_ < 2; ++n_) \
        _Pragma("unroll") for (int kk_ = 0; kk_ < 2; ++kk_) \
          acc[j_][2 + n_] = __builtin_amdgcn_mfma_f32_16x16x32_bf16( \
              af_[j_][kk_], bg_[n_][kk_], acc[j_][2 + n_], 0, 0, 0); \
    __builtin_amdgcn_s_setprio(0); }

  f4 acc[4][4] = {};
  const int ntiles = K >> 6;           // 16
  STG_TILE(0, 0);
  STG_TILE(1, 1);
  WAIT_VM(6);
  BARR;
#pragma unroll 1
  for (int i = 0; i < (ntiles >> 1); ++i) {
    const int e = 2 * i, o = 2 * i + 1;
    const int se = e % 3, so = o % 3;
    if (e + 2 < ntiles) { const int s2 = (e + 2) % 3; STG_TILE(s2, e + 2); }
    COMPUTE_HALF(se);
    if (e + 2 < ntiles) { WAIT_VM(6); } else { WAIT_VM(0); }
    BARR;
    if (o + 2 < ntiles) { const int s2 = (o + 2) % 3; STG_TILE(s2, o + 2); }
    COMPUTE_HALF(so);
    if (o + 2 < ntiles) WAIT_VM(6);
    BARR;
  }

  if (MODE == 1) {
#pragma unroll
    for (int mi = 0; mi < 4; ++mi)
#pragma unroll
      for (int ni = 0; ni < 4; ++ni)
#pragma unroll
        for (int r = 0; r < 4; ++r) {
          long row = bm + wm * 64 + mi * 16 + quad * 4 + r;
          long col = bn + wn * 64 + ni * 16 + lm;
          Cf[row * 1024 + col] = acc[mi][ni][r];
        }
  } else if (bn < 2048) {
    __bf16* dst = (bn < 1024) ? qb : kb;
    const float scl = (bn < 1024) ? QSCALE : 1.0f;
    const int nb = bn & 1023;
#pragma unroll
    for (int mi = 0; mi < 4; ++mi)
#pragma unroll
      for (int ni = 0; ni < 4; ++ni)
#pragma unroll
        for (int r = 0; r < 4; ++r) {
          long row = bm + wm * 64 + mi * 16 + quad * 4 + r;
          long col = nb + wn * 64 + ni * 16 + lm;
          dst[row * 1024 + col] = (__bf16)(acc[mi][ni][r] * scl);
        }
  } else {
#pragma unroll
    for (int mi = 0; mi < 4; ++mi)
#pragma unroll
      for (int ni = 0; ni < 4; ++ni)
#pragma unroll
        for (int r = 0; r < 4; ++r) {
          int d = wn * 64 + ni * 16 + lm;
          int tp = wm * 64 + (quad * 4 + r) * 4 + mi;
          lds[d * 130 + tp] = (__bf16)acc[mi][ni][r];
        }
    __syncthreads();
    const int bloc = bm >> 11;
    const int tloc = bm & 2047;
#pragma unroll
    for (int p = 0; p < 8; ++p) {
      int d = (tid >> 4) + p * 32;
      int c = (tid & 15) * 8;
      long dglob = (bn - 2048) + d;
      *(bfrag*)(vt + ((long)bloc * 1024 + dglob) * 2048 + tloc + c) =
          *(const bfrag*)(lds + d * 130 + c);
    }
  }
}

// ---------- fallback GEMM (f32 A / f32 B, inline convert) ----------
template <bool A_F32, bool OUT_F32>
__global__ __launch_bounds__(256) void gemm_bt_cv(
    const void* __restrict__ Ap, const float* __restrict__ Bp,
    void* __restrict__ Cp, int M, int N, int K, float scl) {
  __shared__ __bf16 As[128 * 32];
  __shared__ __bf16 Bs[128 * 32];
  const int tid = threadIdx.x;
  const int lane = tid & 63, wave = tid >> 6;
  const int lm = lane & 15, quad = lane >> 4;
  const int bm = blockIdx.x * 128, bn = blockIdx.y * 128;
  const int wr = (wave >> 1) * 64, wc = (wave & 1) * 64;
  const int e0 = tid * 16, sr = e0 >> 5, sc = e0 & 31;
  f4 acc[4][4] = {};
  for (int k0 = 0; k0 < K; k0 += 32) {
    if (A_F32) {
      const float4* ga = (const float4*)((const float*)Ap + (long)(bm + sr) * K + k0 + sc);
#pragma unroll
      for (int j = 0; j < 4; ++j) {
        float4 v = ga[j];
        As[sr * 32 + sc + j * 4 + 0] = (__bf16)v.x;
        As[sr * 32 + sc + j * 4 + 1] = (__bf16)v.y;
        As[sr * 32 + sc + j * 4 + 2] = (__bf16)v.z;
        As[sr * 32 + sc + j * 4 + 3] = (__bf16)v.w;
      }
    } else {
      const __bf16* Ab = (const __bf16*)Ap + (long)(bm + sr) * K + k0 + sc;
      *(bfrag*)(As + sr * 32 + sc) = *(const bfrag*)Ab;
      *(bfrag*)(As + sr * 32 + sc + 8) = *(const bfrag*)(Ab + 8);
    }
    {
      const float4* gb = (const float4*)(Bp + (long)(bn + sr) * K + k0 + sc);
#pragma unroll
      for (int j = 0; j < 4; ++j) {
        float4 v = gb[j];
        Bs[sr * 32 + sc + j * 4 + 0] = (__bf16)v.x;
        Bs[sr * 32 + sc + j * 4 + 1] = (__bf16)v.y;
        Bs[sr * 32 + sc + j * 4 + 2] = (__bf16)v.z;
        Bs[sr * 32 + sc + j * 4 + 3] = (__bf16)v.w;
      }
    }
    __syncthreads();
    bfrag af[4], bg[4];
#pragma unroll
    for (int mi = 0; mi < 4; ++mi)
      af[mi] = *(const bfrag*)(As + (wr + mi * 16 + lm) * 32 + quad * 8);
#pragma unroll
    for (int ni = 0; ni < 4; ++ni)
      bg[ni] = *(const bfrag*)(Bs + (wc + ni * 16 + lm) * 32 + quad * 8);
#pragma unroll
    for (int mi = 0; mi < 4; ++mi)
#pragma unroll
      for (int ni = 0; ni < 4; ++ni)
        acc[mi][ni] = __builtin_amdgcn_mfma_f32_16x16x32_bf16(af[mi], bg[ni], acc[mi][ni], 0, 0, 0);
    __syncthreads();
  }
#pragma unroll
  for (int mi = 0; mi < 4; ++mi)
#pragma unroll
    for (int ni = 0; ni < 4; ++ni)
#pragma unroll
      for (int r = 0; r < 4; ++r) {
        long row = bm + wr + mi * 16 + quad * 4 + r;
        long col = bn + wc + ni * 16 + lm;
        if (OUT_F32) ((float*)Cp)[row * N + col] = acc[mi][ni][r] * scl;
        else ((__bf16*)Cp)[row * N + col] = (__bf16)(acc[mi][ni][r] * scl);
      }
}

// ---------- flash attention v12: v10 body, occupancy-split grid ----------
// v10 (proven) was grid-capped at 2 blocks/CU (512 blocks) while LDS/VGPR
// allowed more — latency-bound with both pipes <50%. v12: one 128-row
// q-tile per block (2 frags/wave), grid 64 x 16 = 1024 blocks; register
// state shrinks ~56 regs (y[2][4], L[2], qf[2][2]) so 3 waves/SIMD fit
// under the safe (256,2) bound (r6 lesson: never force min-waves beyond
// the natural register need). qt = 15 - blockIdx.y launches long blocks
// first (work ~ qt+1; longest block 32 k-iters << 68 k-iters/CU total).
// All addressing/swizzles byte-identical to v10. LDS 32 KB.
template <bool VT>
__global__ __launch_bounds__(256, 2) void attn_fwd12(
    const __bf16* Qg, const __bf16* __restrict__ Kg,
    const __bf16* __restrict__ Vsrc, __bf16* Yg) {
  const int TT = 2048, CC = 1024;
  __shared__ __bf16 Ks[64 * 64];        // 8 KB, swizzled
  __shared__ __bf16 Vs[64 * 64];        // 8 KB, swizzled (V^T kappa')
  __shared__ __bf16 Ps[8 * 1024];       // 16 KB: 4 waves x 2 frag regions
  const int tid = threadIdx.x;
  const int wave = tid >> 6, lane = tid & 63;
  const int lm = lane & 15, quad = lane >> 4;
  const int bh = blockIdx.x;
  const int qt = 15 - blockIdx.y;       // longest blocks dispatch first
  const int b = bh >> 4, h = bh & 15;
  const long rbase = (long)b * TT;
  const int hoff = h * 64;
  int row0[2];
  row0[0] = qt * 128 + wave * 16;
  row0[1] = qt * 128 + 64 + wave * 16;
  __bf16* Pw[2];
#pragma unroll
  for (int fr = 0; fr < 2; ++fr) Pw[fr] = Ps + (wave * 2 + fr) * 1024;
  bfrag qf[2][2];
#pragma unroll
  for (int fr = 0; fr < 2; ++fr)
#pragma unroll
    for (int f = 0; f < 2; ++f)
      qf[fr][f] = *(const bfrag*)(Qg + (rbase + row0[fr] + lm) * CC + hoff + f * 32 + quad * 8);
  bfrag ones;
#pragma unroll
  for (int j = 0; j < 8; ++j) ones[j] = (__bf16)1.0f;
  f4 y[2][4] = {};
  f4 L[2] = {};

  const int psl = ((tid & 7) ^ ((tid >> 3) & 7)) * 8;
  const int rsw = lm & 7;

  const int ktLast = 2 * qt + 1;
  bfrag kin[2], vin[2];
#pragma unroll
  for (int s = 0; s < 2; ++s) {
    int idx = tid + s * 256;
    int r = idx >> 3, c = (idx & 7) * 8;
    kin[s] = *(const bfrag*)(Kg + (rbase + r) * CC + hoff + c);
    if (VT)
      vin[s] = *(const bfrag*)(Vsrc + ((long)b * 1024 + hoff + r) * 2048 + c);
    else
      vin[s] = *(const bfrag*)(Vsrc + (rbase + r) * CC + hoff + c);
  }

  for (int kt = 0; kt <= ktLast; ++kt) {
    const int kBase = kt * 64;
    __syncthreads();
#pragma unroll
    for (int s = 0; s < 2; ++s) {
      int idx = tid + s * 256;
      int r = idx >> 3, c = (idx & 7) * 8;
      *(bfrag*)(Ks + r * 64 + psl) = kin[s];
      if (VT) {
        *(bfrag*)(Vs + r * 64 + psl) = vin[s];
      } else {
        int kp = (r & 15) * 4 + (r >> 4);
#pragma unroll
        for (int j = 0; j < 8; ++j)
          Vs[(c + j) * 64 + ((kp >> 3) ^ ((c + j) & 7)) * 8 + (kp & 7)] = vin[s][j];
      }
    }
    const bool more = (kt < ktLast);
    bfrag kin2[2], vin2[2];
    if (more) {
      const int nB = kBase + 64;
#pragma unroll
      for (int s = 0; s < 2; ++s) {
        int idx = tid + s * 256;
        int r = idx >> 3, c = (idx & 7) * 8;
        kin2[s] = *(const bfrag*)(Kg + (rbase + nB + r) * CC + hoff + c);
        if (VT)
          vin2[s] = *(const bfrag*)(Vsrc + ((long)b * 1024 + hoff + r) * 2048 + nB + c);
        else
          vin2[s] = *(const bfrag*)(Vsrc + (rbase + nB + r) * CC + hoff + c);
      }
    }
    __syncthreads();
    bfrag kf[8];
#pragma unroll
    for (int sub = 0; sub < 4; ++sub)
#pragma unroll
      for (int f = 0; f < 2; ++f)
        kf[sub * 2 + f] = *(const bfrag*)(Ks + (sub * 16 + lm) * 64 + ((f * 4 + quad) ^ rsw) * 8);
#pragma unroll
    for (int fr = 0; fr < 2; ++fr) {
      if (kBase <= row0[fr] + 15) {
        f4 sac[4];
#pragma unroll
        for (int sub = 0; sub < 4; ++sub) {
          f4 z = {};
#pragma unroll
          for (int f = 0; f < 2; ++f)
            z = __builtin_amdgcn_mfma_f32_16x16x32_bf16(qf[fr][f], kf[sub * 2 + f], z, 0, 0, 0);
          sac[sub] = z;
        }
        if (kBase + 63 > row0[fr]) {
#pragma unroll
          for (int r = 0; r < 4; ++r) {
            int prow = quad * 4 + r;
            bh4 pk;
#pragma unroll
            for (int sub = 0; sub < 4; ++sub) {
              float pv = __builtin_amdgcn_exp2f(sac[sub][r]);
              bool masked = (kBase + sub * 16 + lm > row0[fr] + prow);
              pk[sub] = (__bf16)(masked ? 0.f : pv);
            }
            *(bh4*)(Pw[fr] + prow * 64 + ((lm >> 1) ^ (prow & 7)) * 8 + (lm & 1) * 4) = pk;
          }
        } else {
#pragma unroll
          for (int r = 0; r < 4; ++r) {
            int prow = quad * 4 + r;
            bh4 pk;
#pragma unroll
            for (int sub = 0; sub < 4; ++sub)
              pk[sub] = (__bf16)__builtin_amdgcn_exp2f(sac[sub][r]);
            *(bh4*)(Pw[fr] + prow * 64 + ((lm >> 1) ^ (prow & 7)) * 8 + (lm & 1) * 4) = pk;
          }
        }
      }
    }
    __asm__ volatile("s_waitcnt lgkmcnt(0)" ::: "memory");
    bfrag vf[8];
#pragma unroll
    for (int sub = 0; sub < 4; ++sub)
#pragma unroll
      for (int f = 0; f < 2; ++f)
        vf[sub * 2 + f] = *(const bfrag*)(Vs + (sub * 16 + lm) * 64 + ((f * 4 + quad) ^ rsw) * 8);
#pragma unroll
    for (int fr = 0; fr < 2; ++fr) {
      if (kBase <= row0[fr] + 15) {
#pragma unroll
        for (int f = 0; f < 2; ++f) {
          bfrag pf = *(const bfrag*)(Pw[fr] + lm * 64 + ((f * 4 + quad) ^ rsw) * 8);
          L[fr] = __builtin_amdgcn_mfma_f32_16x16x32_bf16(pf, ones, L[fr], 0, 0, 0);
#pragma unroll
          for (int ds = 0; ds < 4; ++ds)
            y[fr][ds] = __builtin_amdgcn_mfma_f32_16x16x32_bf16(pf, vf[ds * 2 + f], y[fr][ds], 0, 0, 0);
        }
      }
    }
    if (more) {
      kin[0] = kin2[0]; kin[1] = kin2[1];
      vin[0] = vin2[0]; vin[1] = vin2[1];
    }
  }
#pragma unroll
  for (int fr = 0; fr < 2; ++fr)
#pragma unroll
    for (int ds = 0; ds < 4; ++ds)
#pragma unroll
      for (int r = 0; r < 4; ++r) {
        long row = rbase + row0[fr] + quad * 4 + r;
        Yg[row * CC + hoff + ds * 16 + lm] = (__bf16)(y[fr][ds][r] / L[fr][r]);
      }
}

extern "C" void kernel_launch(void* const* d_in, const int* in_sizes, int n_in,
                              void* d_out, int out_size, void* d_ws, size_t ws_size,
                              hipStream_t stream) {
  (void)in_sizes; (void)n_in; (void)out_size;
  const float* x  = (const float*)d_in[0];
  const float* Wq = (const float*)d_in[1];
  const float* Wk = (const float*)d_in[2];
  const float* Wv = (const float*)d_in[3];
  const float* Wp = (const float*)d_in[4];
  float* out = (float*)d_out;
  const long R = 8192;             // B*T
  const long BUF = R * 1024;
  const long WN = 1024L * 1024;
  __bf16* qb = (__bf16*)d_ws;      // q (pre-scaled), then y in-place
  __bf16* kb = (__bf16*)d_out;     // k + vt borrow d_out (dead before final GEMM)
  __bf16* vslot = kb + BUF;
  dim3 blk(256, 1, 1);
  const size_t need = (size_t)(2 * BUF + 4 * WN) * 2;
  if (ws_size >= need) {
    __bf16* xb = qb + BUF;
    __bf16* wqkv = xb + BUF;       // Wq,Wk,Wv contiguous = [3072][1024]
    __bf16* wpb = wqkv + 3 * WN;
    cvt5<<<dim3((unsigned)(BUF / (256 * 8)), 5, 1), blk, 0, stream>>>(
        x, Wq, Wk, Wv, Wp, xb, wqkv, wqkv + WN, wqkv + 2 * WN, wpb, BUF, WN);
    gemm_dp<0><<<dim3(64, 12, 1), dim3(512, 1, 1), 0, stream>>>(
        xb, wqkv, qb, kb, vslot, nullptr, 1024);
    attn_fwd12<true><<<dim3(64, 16, 1), blk, 0, stream>>>(qb, kb, vslot, qb);
    gemm_dp<1><<<dim3(64, 4, 1), dim3(512, 1, 1), 0, stream>>>(
        qb, wpb, nullptr, nullptr, nullptr, out, 1024);
  } else {
    gemm_bt_cv<true, false><<<dim3(64, 8, 1), blk, 0, stream>>>(x, Wq, qb, 8192, 1024, 1024, QSCALE);
    gemm_bt_cv<true, false><<<dim3(64, 8, 1), blk, 0, stream>>>(x, Wk, kb, 8192, 1024, 1024, 1.0f);
    gemm_bt_cv<true, false><<<dim3(64, 8, 1), blk, 0, stream>>>(x, Wv, vslot, 8192, 1024, 1024, 1.0f);
    attn_fwd12<false><<<dim3(64, 16, 1), blk, 0, stream>>>(qb, kb, vslot, qb);
    gemm_bt_cv<false, true><<<dim3(64, 8, 1), blk, 0, stream>>>(qb, Wp, out, 8192, 1024, 1024, 1.0f);
  }
}

// Round 10
// 227.230 us; speedup vs baseline: 1.1736x; 1.0268x over previous
//
#include <hip/hip_runtime.h>

typedef __bf16 bfrag __attribute__((ext_vector_type(8)));
typedef __bf16 bh4 __attribute__((ext_vector_type(4)));
typedef float f4 __attribute__((ext_vector_type(4)));

#define AS1C(p) (const __attribute__((address_space(1))) void*)(p)
#define AS3(p)  (__attribute__((address_space(3))) void*)(p)

// 0.125 (=1/sqrt(64)) * log2(e): folded into Q so softmax is a bare exp2
#define QSCALE 0.18033688011112042f

__device__ __forceinline__ void g2l16(const __bf16* g, __bf16* l) {
  __builtin_amdgcn_global_load_lds(AS1C(g), AS3(l), 16, 0, 0);
}

// ---------- f32 -> bf16 bulk convert: x + 4 weights in one dispatch ----------
__global__ __launch_bounds__(256) void cvt5(
    const float* __restrict__ s0, const float* __restrict__ s1,
    const float* __restrict__ s2, const float* __restrict__ s3,
    const float* __restrict__ s4,
    __bf16* __restrict__ d0, __bf16* __restrict__ d1, __bf16* __restrict__ d2,
    __bf16* __restrict__ d3, __bf16* __restrict__ d4, long n0, long n1) {
  const float* s; __bf16* d; long n;
  switch (blockIdx.y) {
    case 0: s = s0; d = d0; n = n0; break;
    case 1: s = s1; d = d1; n = n1; break;
    case 2: s = s2; d = d2; n = n1; break;
    case 3: s = s3; d = d3; n = n1; break;
    default: s = s4; d = d4; n = n1; break;
  }
  long i = ((long)blockIdx.x * 256 + threadIdx.x) * 8;
  if (i >= n) return;
  float4 a = *(const float4*)(s + i);
  float4 b = *(const float4*)(s + i + 4);
  bfrag o;
  o[0] = (__bf16)a.x; o[1] = (__bf16)a.y; o[2] = (__bf16)a.z; o[3] = (__bf16)a.w;
  o[4] = (__bf16)b.x; o[5] = (__bf16)b.y; o[6] = (__bf16)b.z; o[7] = (__bf16)b.w;
  *(bfrag*)(d + i) = o;
}

#define BARR __builtin_amdgcn_s_barrier()
#define WAIT_LGKM { asm volatile("s_waitcnt lgkmcnt(0)" ::: "memory"); \
                    __builtin_amdgcn_sched_barrier(0); }
#define WAIT_VM(N) asm volatile("s_waitcnt vmcnt(" #N ")" ::: "memory")

// ============ deep-pipeline GEMM: 128x256 tile, TRIPLE-buffered BK=64 ======
// Best measured GEMM variant (r3: 65.4us). Stage tile t+2 while computing
// tile t; vmcnt(6); 2 barriers per 2 K-tiles; T2 swizzle.
template <int MODE>  // 0: QKV epilogue (by bn), 1: f32 C store (projection)
__global__ __launch_bounds__(512, 2) void gemm_dp(
    const __bf16* __restrict__ A, const __bf16* __restrict__ Bw,
    __bf16* __restrict__ qb, __bf16* __restrict__ kb,
    __bf16* __restrict__ vt, float* __restrict__ Cf, int K) {
  __shared__ __bf16 lds[73728];          // A: 3x8192 | B: 3x16384 (144 KiB)
  __bf16* ldsA = lds;
  __bf16* ldsB = lds + 24576;
  const int tid = threadIdx.x;
  const int wave = tid >> 6, lane = tid & 63;
  const int lm = lane & 15, quad = lane >> 4;
  const int wm = wave >> 2, wn = wave & 3;   // 2m x 4n waves, 64x64 each
  const int bm = blockIdx.x * 128, bn = blockIdx.y * 256;
  const int srow = lane >> 3;                // staging row-within-16
  const int scol = ((lane & 7) ^ srow) * 8;  // pre-swizzled source col
  const int rsw = lm & 7;                    // read-side swizzle key

#define STG_A9(sl, kt) { \
    const __bf16* gp_ = A + (long)(bm + wave * 16 + srow) * K + (kt) * 64 + scol; \
    __bf16* lp_ = ldsA + (sl) * 8192 + wave * 1024 + lane * 8; \
    g2l16(gp_, lp_); g2l16(gp_ + 8 * K, lp_ + 512); }
#define STG_B9(sl, kt, h) { \
    const __bf16* gp_ = Bw + (long)(bn + (h) * 128 + wave * 16 + srow) * K + (kt) * 64 + scol; \
    __bf16* lp_ = ldsB + (sl) * 16384 + (h) * 8192 + wave * 1024 + lane * 8; \
    g2l16(gp_, lp_); g2l16(gp_ + 8 * K, lp_ + 512); }
#define STG_TILE(sl, kt) { STG_A9(sl, kt); STG_B9(sl, kt, 0); STG_B9(sl, kt, 1); }

#define COMPUTE_HALF(sl) { \
    const __bf16* Ab_ = ldsA + (sl) * 8192 + (wm * 64 + lm) * 64; \
    const __bf16* Bb_ = ldsB + (sl) * 16384 + (wn * 64 + lm) * 64; \
    bfrag af_[4][2], bg_[2][2]; \
    _Pragma("unroll") for (int j_ = 0; j_ < 4; ++j_) \
      _Pragma("unroll") for (int kk_ = 0; kk_ < 2; ++kk_) \
        af_[j_][kk_] = *(const bfrag*)(Ab_ + j_ * 1024 + ((kk_ * 4 + quad) ^ rsw) * 8); \
    _Pragma("unroll") for (int n_ = 0; n_ < 2; ++n_) \
      _Pragma("unroll") for (int kk_ = 0; kk_ < 2; ++kk_) \
        bg_[n_][kk_] = *(const bfrag*)(Bb_ + n_ * 1024 + ((kk_ * 4 + quad) ^ rsw) * 8); \
    WAIT_LGKM; \
    __builtin_amdgcn_s_setprio(1); \
    _Pragma("unroll") for (int j_ = 0; j_ < 4; ++j_) \
      _Pragma("unroll") for (int n_ = 0; n_ < 2; ++n_) \
        _Pragma("unroll") for (int kk_ = 0; kk_ < 2; ++kk_) \
          acc[j_][n_] = __builtin_amdgcn_mfma_f32_16x16x32_bf16( \
              af_[j_][kk_], bg_[n_][kk_], acc[j_][n_], 0, 0, 0); \
    __builtin_amdgcn_s_setprio(0); \
    _Pragma("unroll") for (int n_ = 0; n_ < 2; ++n_) \
      _Pragma("unroll") for (int kk_ = 0; kk_ < 2; ++kk_) \
        bg_[n_][kk_] = *(const bfrag*)(Bb_ + (2 + n_) * 1024 + ((kk_ * 4 + quad) ^ rsw) * 8); \
    WAIT_LGKM; \
    __builtin_amdgcn_s_setprio(1); \
    _Pragma("unroll") for (int j_ = 0; j_ < 4; ++j_) \
      _Pragma("unroll") for (int n_ = 0; n_ < 2; ++n_) \
        _Pragma("unroll") for (int kk_ = 0; kk_ < 2; ++kk_) \
          acc[j_][2 + n_] = __builtin_amdgcn_mfma_f32_16x16x32_bf16( \
              af_[j_][kk_], bg_[n_][kk_], acc[j_][2 + n_], 0, 0, 0); \
    __builtin_amdgcn_s_setprio(0); }

  f4 acc[4][4] = {};
  const int ntiles = K >> 6;           // 16
  STG_TILE(0, 0);
  STG_TILE(1, 1);
  WAIT_VM(6);
  BARR;
#pragma unroll 1
  for (int i = 0; i < (ntiles >> 1); ++i) {
    const int e = 2 * i, o = 2 * i + 1;
    const int se = e % 3, so = o % 3;
    if (e + 2 < ntiles) { const int s2 = (e + 2) % 3; STG_TILE(s2, e + 2); }
    COMPUTE_HALF(se);
    if (e + 2 < ntiles) { WAIT_VM(6); } else { WAIT_VM(0); }
    BARR;
    if (o + 2 < ntiles) { const int s2 = (o + 2) % 3; STG_TILE(s2, o + 2); }
    COMPUTE_HALF(so);
    if (o + 2 < ntiles) WAIT_VM(6);
    BARR;
  }

  if (MODE == 1) {
#pragma unroll
    for (int mi = 0; mi < 4; ++mi)
#pragma unroll
      for (int ni = 0; ni < 4; ++ni)
#pragma unroll
        for (int r = 0; r < 4; ++r) {
          long row = bm + wm * 64 + mi * 16 + quad * 4 + r;
          long col = bn + wn * 64 + ni * 16 + lm;
          Cf[row * 1024 + col] = acc[mi][ni][r];
        }
  } else if (bn < 2048) {
    __bf16* dst = (bn < 1024) ? qb : kb;
    const float scl = (bn < 1024) ? QSCALE : 1.0f;
    const int nb = bn & 1023;
#pragma unroll
    for (int mi = 0; mi < 4; ++mi)
#pragma unroll
      for (int ni = 0; ni < 4; ++ni)
#pragma unroll
        for (int r = 0; r < 4; ++r) {
          long row = bm + wm * 64 + mi * 16 + quad * 4 + r;
          long col = nb + wn * 64 + ni * 16 + lm;
          dst[row * 1024 + col] = (__bf16)(acc[mi][ni][r] * scl);
        }
  } else {
#pragma unroll
    for (int mi = 0; mi < 4; ++mi)
#pragma unroll
      for (int ni = 0; ni < 4; ++ni)
#pragma unroll
        for (int r = 0; r < 4; ++r) {
          int d = wn * 64 + ni * 16 + lm;
          int tp = wm * 64 + (quad * 4 + r) * 4 + mi;
          lds[d * 130 + tp] = (__bf16)acc[mi][ni][r];
        }
    __syncthreads();
    const int bloc = bm >> 11;
    const int tloc = bm & 2047;
#pragma unroll
    for (int p = 0; p < 8; ++p) {
      int d = (tid >> 4) + p * 32;
      int c = (tid & 15) * 8;
      long dglob = (bn - 2048) + d;
      *(bfrag*)(vt + ((long)bloc * 1024 + dglob) * 2048 + tloc + c) =
          *(const bfrag*)(lds + d * 130 + c);
    }
  }
}

// ---------- fallback GEMM (f32 A / f32 B, inline convert) ----------
template <bool A_F32, bool OUT_F32>
__global__ __launch_bounds__(256) void gemm_bt_cv(
    const void* __restrict__ Ap, const float* __restrict__ Bp,
    void* __restrict__ Cp, int M, int N, int K, float scl) {
  __shared__ __bf16 As[128 * 32];
  __shared__ __bf16 Bs[128 * 32];
  const int tid = threadIdx.x;
  const int lane = tid & 63, wave = tid >> 6;
  const int lm = lane & 15, quad = lane >> 4;
  const int bm = blockIdx.x * 128, bn = blockIdx.y * 128;
  const int wr = (wave >> 1) * 64, wc = (wave & 1) * 64;
  const int e0 = tid * 16, sr = e0 >> 5, sc = e0 & 31;
  f4 acc[4][4] = {};
  for (int k0 = 0; k0 < K; k0 += 32) {
    if (A_F32) {
      const float4* ga = (const float4*)((const float*)Ap + (long)(bm + sr) * K + k0 + sc);
#pragma unroll
      for (int j = 0; j < 4; ++j) {
        float4 v = ga[j];
        As[sr * 32 + sc + j * 4 + 0] = (__bf16)v.x;
        As[sr * 32 + sc + j * 4 + 1] = (__bf16)v.y;
        As[sr * 32 + sc + j * 4 + 2] = (__bf16)v.z;
        As[sr * 32 + sc + j * 4 + 3] = (__bf16)v.w;
      }
    } else {
      const __bf16* Ab = (const __bf16*)Ap + (long)(bm + sr) * K + k0 + sc;
      *(bfrag*)(As + sr * 32 + sc) = *(const bfrag*)Ab;
      *(bfrag*)(As + sr * 32 + sc + 8) = *(const bfrag*)(Ab + 8);
    }
    {
      const float4* gb = (const float4*)(Bp + (long)(bn + sr) * K + k0 + sc);
#pragma unroll
      for (int j = 0; j < 4; ++j) {
        float4 v = gb[j];
        Bs[sr * 32 + sc + j * 4 + 0] = (__bf16)v.x;
        Bs[sr * 32 + sc + j * 4 + 1] = (__bf16)v.y;
        Bs[sr * 32 + sc + j * 4 + 2] = (__bf16)v.z;
        Bs[sr * 32 + sc + j * 4 + 3] = (__bf16)v.w;
      }
    }
    __syncthreads();
    bfrag af[4], bg[4];
#pragma unroll
    for (int mi = 0; mi < 4; ++mi)
      af[mi] = *(const bfrag*)(As + (wr + mi * 16 + lm) * 32 + quad * 8);
#pragma unroll
    for (int ni = 0; ni < 4; ++ni)
      bg[ni] = *(const bfrag*)(Bs + (wc + ni * 16 + lm) * 32 + quad * 8);
#pragma unroll
    for (int mi = 0; mi < 4; ++mi)
#pragma unroll
      for (int ni = 0; ni < 4; ++ni)
        acc[mi][ni] = __builtin_amdgcn_mfma_f32_16x16x32_bf16(af[mi], bg[ni], acc[mi][ni], 0, 0, 0);
    __syncthreads();
  }
#pragma unroll
  for (int mi = 0; mi < 4; ++mi)
#pragma unroll
    for (int ni = 0; ni < 4; ++ni)
#pragma unroll
      for (int r = 0; r < 4; ++r) {
        long row = bm + wr + mi * 16 + quad * 4 + r;
        long col = bn + wc + ni * 16 + lm;
        if (OUT_F32) ((float*)Cp)[row * N + col] = acc[mi][ni][r] * scl;
        else ((__bf16*)Cp)[row * N + col] = (__bf16)(acc[mi][ni][r] * scl);
      }
}

// ---------- flash attention v13: v10 pairing, 8-wave split ----------
// v10 economics (paired tiles {i,15-i}: 200 k-iters/bh) + v12's measured
// 2-frag register state (88 VGPR). Each pair is handled by ONE 512-thread
// block: 8 waves x 16 rows cover each 128-row tile; wave w owns frag 0
// (rows qtA*128+w*16) and frag 1 (rows qtB*128+w*16). Grid 64x8 = 512
// blocks x 8 waves = 16 waves/CU = 4 waves/SIMD — 2x v10's TLP on a
// latency-bound kernel, with staging traffic per bh unchanged (same
// tiles staged once per pair-block, half per thread). All addressing /
// swizzle formulas byte-identical to v10.
template <bool VT>
__global__ __launch_bounds__(512, 2) void attn_fwd13(
    const __bf16* Qg, const __bf16* __restrict__ Kg,
    const __bf16* __restrict__ Vsrc, __bf16* Yg) {
  const int TT = 2048, CC = 1024;
  __shared__ __bf16 Ks[64 * 64];        // 8 KB, swizzled
  __shared__ __bf16 Vs[64 * 64];        // 8 KB, swizzled (V^T kappa')
  __shared__ __bf16 Ps[16 * 1024];      // 32 KB: 8 waves x 2 frag regions
  const int tid = threadIdx.x;
  const int wave = tid >> 6, lane = tid & 63;
  const int lm = lane & 15, quad = lane >> 4;
  const int bh = blockIdx.x, i = blockIdx.y;
  const int b = bh >> 4, h = bh & 15;
  const int qtA = i, qtB = 15 - i;
  const long rbase = (long)b * TT;
  const int hoff = h * 64;
  int row0[2];
  row0[0] = qtA * 128 + wave * 16;
  row0[1] = qtB * 128 + wave * 16;
  __bf16* Pw[2];
#pragma unroll
  for (int fr = 0; fr < 2; ++fr) Pw[fr] = Ps + (wave * 2 + fr) * 1024;
  bfrag qf[2][2];
#pragma unroll
  for (int fr = 0; fr < 2; ++fr)
#pragma unroll
    for (int f = 0; f < 2; ++f)
      qf[fr][f] = *(const bfrag*)(Qg + (rbase + row0[fr] + lm) * CC + hoff + f * 32 + quad * 8);
  bfrag ones;
#pragma unroll
  for (int j = 0; j < 8; ++j) ones[j] = (__bf16)1.0f;
  f4 y[2][4] = {};
  f4 L[2] = {};

  // staging: 512 threads, 1 bfrag K + 1 bfrag V each. row = tid>>3 (0..63),
  // slot = tid&7; row&7 == (tid>>3)&7 -> physical slot constant per thread.
  const int psl = ((tid & 7) ^ ((tid >> 3) & 7)) * 8;
  const int rsw = lm & 7;  // read-side swizzle key (row&7 == lm&7 for frags)

  const int ktLast = 2 * qtB + 1;
  const int sr = tid >> 3, scc = (tid & 7) * 8;
  bfrag kin, vin;
  kin = *(const bfrag*)(Kg + (rbase + sr) * CC + hoff + scc);
  if (VT)
    vin = *(const bfrag*)(Vsrc + ((long)b * 1024 + hoff + sr) * 2048 + scc);
  else
    vin = *(const bfrag*)(Vsrc + (rbase + sr) * CC + hoff + scc);

  for (int kt = 0; kt <= ktLast; ++kt) {
    const int kBase = kt * 64;
    __syncthreads();
    *(bfrag*)(Ks + sr * 64 + psl) = kin;
    if (VT) {
      *(bfrag*)(Vs + sr * 64 + psl) = vin;
    } else {
      int kp = (sr & 15) * 4 + (sr >> 4);
#pragma unroll
      for (int j = 0; j < 8; ++j)
        Vs[(scc + j) * 64 + ((kp >> 3) ^ ((scc + j) & 7)) * 8 + (kp & 7)] = vin[j];
    }
    const bool more = (kt < ktLast);
    bfrag kin2, vin2;
    if (more) {
      const int nB = kBase + 64;
      kin2 = *(const bfrag*)(Kg + (rbase + nB + sr) * CC + hoff + scc);
      if (VT)
        vin2 = *(const bfrag*)(Vsrc + ((long)b * 1024 + hoff + sr) * 2048 + nB + scc);
      else
        vin2 = *(const bfrag*)(Vsrc + (rbase + nB + sr) * CC + hoff + scc);
    }
    __syncthreads();
    bfrag kf[8];
#pragma unroll
    for (int sub = 0; sub < 4; ++sub)
#pragma unroll
      for (int f = 0; f < 2; ++f)
        kf[sub * 2 + f] = *(const bfrag*)(Ks + (sub * 16 + lm) * 64 + ((f * 4 + quad) ^ rsw) * 8);
#pragma unroll
    for (int fr = 0; fr < 2; ++fr) {
      if (kBase <= row0[fr] + 15) {
        f4 sac[4];
#pragma unroll
        for (int sub = 0; sub < 4; ++sub) {
          f4 z = {};
#pragma unroll
          for (int f = 0; f < 2; ++f)
            z = __builtin_amdgcn_mfma_f32_16x16x32_bf16(qf[fr][f], kf[sub * 2 + f], z, 0, 0, 0);
          sac[sub] = z;
        }
        if (kBase + 63 > row0[fr]) {
#pragma unroll
          for (int r = 0; r < 4; ++r) {
            int prow = quad * 4 + r;
            bh4 pk;
#pragma unroll
            for (int sub = 0; sub < 4; ++sub) {
              float pv = __builtin_amdgcn_exp2f(sac[sub][r]);
              bool masked = (kBase + sub * 16 + lm > row0[fr] + prow);
              pk[sub] = (__bf16)(masked ? 0.f : pv);
            }
            *(bh4*)(Pw[fr] + prow * 64 + ((lm >> 1) ^ (prow & 7)) * 8 + (lm & 1) * 4) = pk;
          }
        } else {
#pragma unroll
          for (int r = 0; r < 4; ++r) {
            int prow = quad * 4 + r;
            bh4 pk;
#pragma unroll
            for (int sub = 0; sub < 4; ++sub)
              pk[sub] = (__bf16)__builtin_amdgcn_exp2f(sac[sub][r]);
            *(bh4*)(Pw[fr] + prow * 64 + ((lm >> 1) ^ (prow & 7)) * 8 + (lm & 1) * 4) = pk;
          }
        }
      }
    }
    __asm__ volatile("s_waitcnt lgkmcnt(0)" ::: "memory");
    bfrag vf[8];
#pragma unroll
    for (int sub = 0; sub < 4; ++sub)
#pragma unroll
      for (int f = 0; f < 2; ++f)
        vf[sub * 2 + f] = *(const bfrag*)(Vs + (sub * 16 + lm) * 64 + ((f * 4 + quad) ^ rsw) * 8);
#pragma unroll
    for (int fr = 0; fr < 2; ++fr) {
      if (kBase <= row0[fr] + 15) {
#pragma unroll
        for (int f = 0; f < 2; ++f) {
          bfrag pf = *(const bfrag*)(Pw[fr] + lm * 64 + ((f * 4 + quad) ^ rsw) * 8);
          L[fr] = __builtin_amdgcn_mfma_f32_16x16x32_bf16(pf, ones, L[fr], 0, 0, 0);
#pragma unroll
          for (int ds = 0; ds < 4; ++ds)
            y[fr][ds] = __builtin_amdgcn_mfma_f32_16x16x32_bf16(pf, vf[ds * 2 + f], y[fr][ds], 0, 0, 0);
        }
      }
    }
    if (more) { kin = kin2; vin = vin2; }
  }
#pragma unroll
  for (int fr = 0; fr < 2; ++fr)
#pragma unroll
    for (int ds = 0; ds < 4; ++ds)
#pragma unroll
      for (int r = 0; r < 4; ++r) {
        long row = rbase + row0[fr] + quad * 4 + r;
        Yg[row * CC + hoff + ds * 16 + lm] = (__bf16)(y[fr][ds][r] / L[fr][r]);
      }
}

extern "C" void kernel_launch(void* const* d_in, const int* in_sizes, int n_in,
                              void* d_out, int out_size, void* d_ws, size_t ws_size,
                              hipStream_t stream) {
  (void)in_sizes; (void)n_in; (void)out_size;
  const float* x  = (const float*)d_in[0];
  const float* Wq = (const float*)d_in[1];
  const float* Wk = (const float*)d_in[2];
  const float* Wv = (const float*)d_in[3];
  const float* Wp = (const float*)d_in[4];
  float* out = (float*)d_out;
  const long R = 8192;             // B*T
  const long BUF = R * 1024;
  const long WN = 1024L * 1024;
  __bf16* qb = (__bf16*)d_ws;      // q (pre-scaled), then y in-place
  __bf16* kb = (__bf16*)d_out;     // k + vt borrow d_out (dead before final GEMM)
  __bf16* vslot = kb + BUF;
  dim3 blk(256, 1, 1);
  const size_t need = (size_t)(2 * BUF + 4 * WN) * 2;
  if (ws_size >= need) {
    __bf16* xb = qb + BUF;
    __bf16* wqkv = xb + BUF;       // Wq,Wk,Wv contiguous = [3072][1024]
    __bf16* wpb = wqkv + 3 * WN;
    cvt5<<<dim3((unsigned)(BUF / (256 * 8)), 5, 1), blk, 0, stream>>>(
        x, Wq, Wk, Wv, Wp, xb, wqkv, wqkv + WN, wqkv + 2 * WN, wpb, BUF, WN);
    gemm_dp<0><<<dim3(64, 12, 1), dim3(512, 1, 1), 0, stream>>>(
        xb, wqkv, qb, kb, vslot, nullptr, 1024);
    attn_fwd13<true><<<dim3(64, 8, 1), dim3(512, 1, 1), 0, stream>>>(qb, kb, vslot, qb);
    gemm_dp<1><<<dim3(64, 4, 1), dim3(512, 1, 1), 0, stream>>>(
        qb, wpb, nullptr, nullptr, nullptr, out, 1024);
  } else {
    gemm_bt_cv<true, false><<<dim3(64, 8, 1), blk, 0, stream>>>(x, Wq, qb, 8192, 1024, 1024, QSCALE);
    gemm_bt_cv<true, false><<<dim3(64, 8, 1), blk, 0, stream>>>(x, Wk, kb, 8192, 1024, 1024, 1.0f);
    gemm_bt_cv<true, false><<<dim3(64, 8, 1), blk, 0, stream>>>(x, Wv, vslot, 8192, 1024, 1024, 1.0f);
    attn_fwd13<false><<<dim3(64, 8, 1), dim3(512, 1, 1), 0, stream>>>(qb, kb, vslot, qb);
    gemm_bt_cv<false, true><<<dim3(64, 8, 1), blk, 0, stream>>>(qb, Wp, out, 8192, 1024, 1024, 1.0f);
  }
}

// Round 11
// 222.956 us; speedup vs baseline: 1.1961x; 1.0192x over previous
//
#include <hip/hip_runtime.h>

typedef __bf16 bfrag __attribute__((ext_vector_type(8)));
typedef __bf16 bh4 __attribute__((ext_vector_type(4)));
typedef float f4 __attribute__((ext_vector_type(4)));

#define AS1C(p) (const __attribute__((address_space(1))) void*)(p)
#define AS3(p)  (__attribute__((address_space(3))) void*)(p)

// 0.125 (=1/sqrt(64)) * log2(e): folded into Q so softmax is a bare exp2
#define QSCALE 0.18033688011112042f

__device__ __forceinline__ void g2l16(const __bf16* g, __bf16* l) {
  __builtin_amdgcn_global_load_lds(AS1C(g), AS3(l), 16, 0, 0);
}

// ---------- f32 -> bf16 bulk convert: x + 4 weights in one dispatch ----------
__global__ __launch_bounds__(256) void cvt5(
    const float* __restrict__ s0, const float* __restrict__ s1,
    const float* __restrict__ s2, const float* __restrict__ s3,
    const float* __restrict__ s4,
    __bf16* __restrict__ d0, __bf16* __restrict__ d1, __bf16* __restrict__ d2,
    __bf16* __restrict__ d3, __bf16* __restrict__ d4, long n0, long n1) {
  const float* s; __bf16* d; long n;
  switch (blockIdx.y) {
    case 0: s = s0; d = d0; n = n0; break;
    case 1: s = s1; d = d1; n = n1; break;
    case 2: s = s2; d = d2; n = n1; break;
    case 3: s = s3; d = d3; n = n1; break;
    default: s = s4; d = d4; n = n1; break;
  }
  long i = ((long)blockIdx.x * 256 + threadIdx.x) * 8;
  if (i >= n) return;
  float4 a = *(const float4*)(s + i);
  float4 b = *(const float4*)(s + i + 4);
  bfrag o;
  o[0] = (__bf16)a.x; o[1] = (__bf16)a.y; o[2] = (__bf16)a.z; o[3] = (__bf16)a.w;
  o[4] = (__bf16)b.x; o[5] = (__bf16)b.y; o[6] = (__bf16)b.z; o[7] = (__bf16)b.w;
  *(bfrag*)(d + i) = o;
}

#define BARR __builtin_amdgcn_s_barrier()
#define WAIT_LGKM { asm volatile("s_waitcnt lgkmcnt(0)" ::: "memory"); \
                    __builtin_amdgcn_sched_barrier(0); }
#define WAIT_VM(N) asm volatile("s_waitcnt vmcnt(" #N ")" ::: "memory")

// ============ deep-pipeline GEMM: 128x256 tile, TRIPLE-buffered BK=64 ======
// Best measured GEMM variant (r3: 65.4us). Stage tile t+2 while computing
// tile t; vmcnt(6); 2 barriers per 2 K-tiles; T2 swizzle.
template <int MODE>  // 0: QKV epilogue (by bn), 1: f32 C store (projection)
__global__ __launch_bounds__(512, 2) void gemm_dp(
    const __bf16* __restrict__ A, const __bf16* __restrict__ Bw,
    __bf16* __restrict__ qb, __bf16* __restrict__ kb,
    __bf16* __restrict__ vt, float* __restrict__ Cf, int K) {
  __shared__ __bf16 lds[73728];          // A: 3x8192 | B: 3x16384 (144 KiB)
  __bf16* ldsA = lds;
  __bf16* ldsB = lds + 24576;
  const int tid = threadIdx.x;
  const int wave = tid >> 6, lane = tid & 63;
  const int lm = lane & 15, quad = lane >> 4;
  const int wm = wave >> 2, wn = wave & 3;   // 2m x 4n waves, 64x64 each
  const int bm = blockIdx.x * 128, bn = blockIdx.y * 256;
  const int srow = lane >> 3;                // staging row-within-16
  const int scol = ((lane & 7) ^ srow) * 8;  // pre-swizzled source col
  const int rsw = lm & 7;                    // read-side swizzle key

#define STG_A9(sl, kt) { \
    const __bf16* gp_ = A + (long)(bm + wave * 16 + srow) * K + (kt) * 64 + scol; \
    __bf16* lp_ = ldsA + (sl) * 8192 + wave * 1024 + lane * 8; \
    g2l16(gp_, lp_); g2l16(gp_ + 8 * K, lp_ + 512); }
#define STG_B9(sl, kt, h) { \
    const __bf16* gp_ = Bw + (long)(bn + (h) * 128 + wave * 16 + srow) * K + (kt) * 64 + scol; \
    __bf16* lp_ = ldsB + (sl) * 16384 + (h) * 8192 + wave * 1024 + lane * 8; \
    g2l16(gp_, lp_); g2l16(gp_ + 8 * K, lp_ + 512); }
#define STG_TILE(sl, kt) { STG_A9(sl, kt); STG_B9(sl, kt, 0); STG_B9(sl, kt, 1); }

#define COMPUTE_HALF(sl) { \
    const __bf16* Ab_ = ldsA + (sl) * 8192 + (wm * 64 + lm) * 64; \
    const __bf16* Bb_ = ldsB + (sl) * 16384 + (wn * 64 + lm) * 64; \
    bfrag af_[4][2], bg_[2][2]; \
    _Pragma("unroll") for (int j_ = 0; j_ < 4; ++j_) \
      _Pragma("unroll") for (int kk_ = 0; kk_ < 2; ++kk_) \
        af_[j_][kk_] = *(const bfrag*)(Ab_ + j_ * 1024 + ((kk_ * 4 + quad) ^ rsw) * 8); \
    _Pragma("unroll") for (int n_ = 0; n_ < 2; ++n_) \
      _Pragma("unroll") for (int kk_ = 0; kk_ < 2; ++kk_) \
        bg_[n_][kk_] = *(const bfrag*)(Bb_ + n_ * 1024 + ((kk_ * 4 + quad) ^ rsw) * 8); \
    WAIT_LGKM; \
    __builtin_amdgcn_s_setprio(1); \
    _Pragma("unroll") for (int j_ = 0; j_ < 4; ++j_) \
      _Pragma("unroll") for (int n_ = 0; n_ < 2; ++n_) \
        _Pragma("unroll") for (int kk_ = 0; kk_ < 2; ++kk_) \
          acc[j_][n_] = __builtin_amdgcn_mfma_f32_16x16x32_bf16( \
              af_[j_][kk_], bg_[n_][kk_], acc[j_][n_], 0, 0, 0); \
    __builtin_amdgcn_s_setprio(0); \
    _Pragma("unroll") for (int n_ = 0; n_ < 2; ++n_) \
      _Pragma("unroll") for (int kk_ = 0; kk_ < 2; ++kk_) \
        bg_[n_][kk_] = *(const bfrag*)(Bb_ + (2 + n_) * 1024 + ((kk_ * 4 + quad) ^ rsw) * 8); \
    WAIT_LGKM; \
    __builtin_amdgcn_s_setprio(1); \
    _Pragma("unroll") for (int j_ = 0; j_ < 4; ++j_) \
      _Pragma("unroll") for (int n_ = 0; n_ < 2; ++n_) \
        _Pragma("unroll") for (int kk_ = 0; kk_ < 2; ++kk_) \
          acc[j_][2 + n_] = __builtin_amdgcn_mfma_f32_16x16x32_bf16( \
              af_[j_][kk_], bg_[n_][kk_], acc[j_][2 + n_], 0, 0, 0); \
    __builtin_amdgcn_s_setprio(0); }

  f4 acc[4][4] = {};
  const int ntiles = K >> 6;           // 16
  STG_TILE(0, 0);
  STG_TILE(1, 1);
  WAIT_VM(6);
  BARR;
#pragma unroll 1
  for (int i = 0; i < (ntiles >> 1); ++i) {
    const int e = 2 * i, o = 2 * i + 1;
    const int se = e % 3, so = o % 3;
    if (e + 2 < ntiles) { const int s2 = (e + 2) % 3; STG_TILE(s2, e + 2); }
    COMPUTE_HALF(se);
    if (e + 2 < ntiles) { WAIT_VM(6); } else { WAIT_VM(0); }
    BARR;
    if (o + 2 < ntiles) { const int s2 = (o + 2) % 3; STG_TILE(s2, o + 2); }
    COMPUTE_HALF(so);
    if (o + 2 < ntiles) WAIT_VM(6);
    BARR;
  }

  if (MODE == 1) {
#pragma unroll
    for (int mi = 0; mi < 4; ++mi)
#pragma unroll
      for (int ni = 0; ni < 4; ++ni)
#pragma unroll
        for (int r = 0; r < 4; ++r) {
          long row = bm + wm * 64 + mi * 16 + quad * 4 + r;
          long col = bn + wn * 64 + ni * 16 + lm;
          Cf[row * 1024 + col] = acc[mi][ni][r];
        }
  } else if (bn < 2048) {
    __bf16* dst = (bn < 1024) ? qb : kb;
    const float scl = (bn < 1024) ? QSCALE : 1.0f;
    const int nb = bn & 1023;
#pragma unroll
    for (int mi = 0; mi < 4; ++mi)
#pragma unroll
      for (int ni = 0; ni < 4; ++ni)
#pragma unroll
        for (int r = 0; r < 4; ++r) {
          long row = bm + wm * 64 + mi * 16 + quad * 4 + r;
          long col = nb + wn * 64 + ni * 16 + lm;
          dst[row * 1024 + col] = (__bf16)(acc[mi][ni][r] * scl);
        }
  } else {
#pragma unroll
    for (int mi = 0; mi < 4; ++mi)
#pragma unroll
      for (int ni = 0; ni < 4; ++ni)
#pragma unroll
        for (int r = 0; r < 4; ++r) {
          int d = wn * 64 + ni * 16 + lm;
          int tp = wm * 64 + (quad * 4 + r) * 4 + mi;
          lds[d * 130 + tp] = (__bf16)acc[mi][ni][r];
        }
    __syncthreads();
    const int bloc = bm >> 11;
    const int tloc = bm & 2047;
#pragma unroll
    for (int p = 0; p < 8; ++p) {
      int d = (tid >> 4) + p * 32;
      int c = (tid & 15) * 8;
      long dglob = (bn - 2048) + d;
      *(bfrag*)(vt + ((long)bloc * 1024 + dglob) * 2048 + tloc + c) =
          *(const bfrag*)(lds + d * 130 + c);
    }
  }
}

// ---------- fallback GEMM (f32 A / f32 B, inline convert) ----------
template <bool A_F32, bool OUT_F32>
__global__ __launch_bounds__(256) void gemm_bt_cv(
    const void* __restrict__ Ap, const float* __restrict__ Bp,
    void* __restrict__ Cp, int M, int N, int K, float scl) {
  __shared__ __bf16 As[128 * 32];
  __shared__ __bf16 Bs[128 * 32];
  const int tid = threadIdx.x;
  const int lane = tid & 63, wave = tid >> 6;
  const int lm = lane & 15, quad = lane >> 4;
  const int bm = blockIdx.x * 128, bn = blockIdx.y * 128;
  const int wr = (wave >> 1) * 64, wc = (wave & 1) * 64;
  const int e0 = tid * 16, sr = e0 >> 5, sc = e0 & 31;
  f4 acc[4][4] = {};
  for (int k0 = 0; k0 < K; k0 += 32) {
    if (A_F32) {
      const float4* ga = (const float4*)((const float*)Ap + (long)(bm + sr) * K + k0 + sc);
#pragma unroll
      for (int j = 0; j < 4; ++j) {
        float4 v = ga[j];
        As[sr * 32 + sc + j * 4 + 0] = (__bf16)v.x;
        As[sr * 32 + sc + j * 4 + 1] = (__bf16)v.y;
        As[sr * 32 + sc + j * 4 + 2] = (__bf16)v.z;
        As[sr * 32 + sc + j * 4 + 3] = (__bf16)v.w;
      }
    } else {
      const __bf16* Ab = (const __bf16*)Ap + (long)(bm + sr) * K + k0 + sc;
      *(bfrag*)(As + sr * 32 + sc) = *(const bfrag*)Ab;
      *(bfrag*)(As + sr * 32 + sc + 8) = *(const bfrag*)(Ab + 8);
    }
    {
      const float4* gb = (const float4*)(Bp + (long)(bn + sr) * K + k0 + sc);
#pragma unroll
      for (int j = 0; j < 4; ++j) {
        float4 v = gb[j];
        Bs[sr * 32 + sc + j * 4 + 0] = (__bf16)v.x;
        Bs[sr * 32 + sc + j * 4 + 1] = (__bf16)v.y;
        Bs[sr * 32 + sc + j * 4 + 2] = (__bf16)v.z;
        Bs[sr * 32 + sc + j * 4 + 3] = (__bf16)v.w;
      }
    }
    __syncthreads();
    bfrag af[4], bg[4];
#pragma unroll
    for (int mi = 0; mi < 4; ++mi)
      af[mi] = *(const bfrag*)(As + (wr + mi * 16 + lm) * 32 + quad * 8);
#pragma unroll
    for (int ni = 0; ni < 4; ++ni)
      bg[ni] = *(const bfrag*)(Bs + (wc + ni * 16 + lm) * 32 + quad * 8);
#pragma unroll
    for (int mi = 0; mi < 4; ++mi)
#pragma unroll
      for (int ni = 0; ni < 4; ++ni)
        acc[mi][ni] = __builtin_amdgcn_mfma_f32_16x16x32_bf16(af[mi], bg[ni], acc[mi][ni], 0, 0, 0);
    __syncthreads();
  }
#pragma unroll
  for (int mi = 0; mi < 4; ++mi)
#pragma unroll
    for (int ni = 0; ni < 4; ++ni)
#pragma unroll
      for (int r = 0; r < 4; ++r) {
        long row = bm + wr + mi * 16 + quad * 4 + r;
        long col = bn + wc + ni * 16 + lm;
        if (OUT_F32) ((float*)Cp)[row * N + col] = acc[mi][ni][r] * scl;
        else ((__bf16*)Cp)[row * N + col] = (__bf16)(acc[mi][ni][r] * scl);
      }
}

// ---------- flash attention v10: KP=64 + XOR slot swizzle, (256,2) --------
// Best measured attn (224.5us total build). Row stride 64 elems (128 B,
// 16B-aligned) with T2 XOR: physical 16B slot = slot ^ (row&7) on
// reg-staged writes AND fragment reads -> K/V/P frag reads <=2-way (free,
// conflicts 7.5M -> 0 measured). Paired q-tiles {i,15-i} (200 k-iters/bh),
// shadow prefetch regs, single lgkm drain per k-iter.
template <bool VT>
__global__ __launch_bounds__(256, 2) void attn_fwd10(
    const __bf16* Qg, const __bf16* __restrict__ Kg,
    const __bf16* __restrict__ Vsrc, __bf16* Yg) {
  const int TT = 2048, CC = 1024;
  __shared__ __bf16 Ks[64 * 64];        // 8 KB, swizzled
  __shared__ __bf16 Vs[64 * 64];        // 8 KB, swizzled (V^T kappa')
  __shared__ __bf16 Ps[16 * 16 * 64];   // 32 KB: 4 waves x 4 frags, swizzled
  const int tid = threadIdx.x;
  const int wave = tid >> 6, lane = tid & 63;
  const int lm = lane & 15, quad = lane >> 4;
  const int bh = blockIdx.x, i = blockIdx.y;
  const int b = bh >> 4, h = bh & 15;
  const int qtA = i, qtB = 15 - i;
  const long rbase = (long)b * TT;
  const int hoff = h * 64;
  int row0[4];
  row0[0] = qtA * 128 + wave * 16;
  row0[1] = qtA * 128 + 64 + wave * 16;
  row0[2] = qtB * 128 + wave * 16;
  row0[3] = qtB * 128 + 64 + wave * 16;
  __bf16* Pw[4];
#pragma unroll
  for (int fr = 0; fr < 4; ++fr) Pw[fr] = Ps + (wave * 4 + fr) * 1024;
  bfrag qf[4][2];
#pragma unroll
  for (int fr = 0; fr < 4; ++fr)
#pragma unroll
    for (int f = 0; f < 2; ++f)
      qf[fr][f] = *(const bfrag*)(Qg + (rbase + row0[fr] + lm) * CC + hoff + f * 32 + quad * 8);
  bfrag ones;
#pragma unroll
  for (int j = 0; j < 8; ++j) ones[j] = (__bf16)1.0f;
  f4 y[4][4] = {};
  f4 L[4] = {};

  // staging geometry: idx = tid + s*256 -> row = (tid>>3)+32s, slot = tid&7.
  // row&7 == (tid>>3)&7 for both s -> physical slot constant per thread.
  const int psl = ((tid & 7) ^ ((tid >> 3) & 7)) * 8;
  const int rsw = lm & 7;  // read-side swizzle key (row&7 == lm&7 for frags)

  const int ktLast = 2 * qtB + 1;
  bfrag kin[2], vin[2];
#pragma unroll
  for (int s = 0; s < 2; ++s) {
    int idx = tid + s * 256;
    int r = idx >> 3, c = (idx & 7) * 8;
    kin[s] = *(const bfrag*)(Kg + (rbase + r) * CC + hoff + c);
    if (VT)
      vin[s] = *(const bfrag*)(Vsrc + ((long)b * 1024 + hoff + r) * 2048 + c);
    else
      vin[s] = *(const bfrag*)(Vsrc + (rbase + r) * CC + hoff + c);
  }

  for (int kt = 0; kt <= ktLast; ++kt) {
    const int kBase = kt * 64;
    __syncthreads();
#pragma unroll
    for (int s = 0; s < 2; ++s) {
      int idx = tid + s * 256;
      int r = idx >> 3, c = (idx & 7) * 8;
      *(bfrag*)(Ks + r * 64 + psl) = kin[s];
      if (VT) {
        *(bfrag*)(Vs + r * 64 + psl) = vin[s];
      } else {
        int kp = (r & 15) * 4 + (r >> 4);
#pragma unroll
        for (int j = 0; j < 8; ++j)
          Vs[(c + j) * 64 + ((kp >> 3) ^ ((c + j) & 7)) * 8 + (kp & 7)] = vin[s][j];
      }
    }
    const bool more = (kt < ktLast);
    bfrag kin2[2], vin2[2];
    if (more) {
      const int nB = kBase + 64;
#pragma unroll
      for (int s = 0; s < 2; ++s) {
        int idx = tid + s * 256;
        int r = idx >> 3, c = (idx & 7) * 8;
        kin2[s] = *(const bfrag*)(Kg + (rbase + nB + r) * CC + hoff + c);
        if (VT)
          vin2[s] = *(const bfrag*)(Vsrc + ((long)b * 1024 + hoff + r) * 2048 + nB + c);
        else
          vin2[s] = *(const bfrag*)(Vsrc + (rbase + nB + r) * CC + hoff + c);
      }
    }
    __syncthreads();
    bfrag kf[8];
#pragma unroll
    for (int sub = 0; sub < 4; ++sub)
#pragma unroll
      for (int f = 0; f < 2; ++f)
        kf[sub * 2 + f] = *(const bfrag*)(Ks + (sub * 16 + lm) * 64 + ((f * 4 + quad) ^ rsw) * 8);
#pragma unroll
    for (int fr = 0; fr < 4; ++fr) {
      if (kBase <= row0[fr] + 15) {
        f4 sac[4];
#pragma unroll
        for (int sub = 0; sub < 4; ++sub) {
          f4 z = {};
#pragma unroll
          for (int f = 0; f < 2; ++f)
            z = __builtin_amdgcn_mfma_f32_16x16x32_bf16(qf[fr][f], kf[sub * 2 + f], z, 0, 0, 0);
          sac[sub] = z;
        }
        if (kBase + 63 > row0[fr]) {
#pragma unroll
          for (int r = 0; r < 4; ++r) {
            int prow = quad * 4 + r;
            bh4 pk;
#pragma unroll
            for (int sub = 0; sub < 4; ++sub) {
              float pv = __builtin_amdgcn_exp2f(sac[sub][r]);
              bool masked = (kBase + sub * 16 + lm > row0[fr] + prow);
              pk[sub] = (__bf16)(masked ? 0.f : pv);
            }
            *(bh4*)(Pw[fr] + prow * 64 + ((lm >> 1) ^ (prow & 7)) * 8 + (lm & 1) * 4) = pk;
          }
        } else {
#pragma unroll
          for (int r = 0; r < 4; ++r) {
            int prow = quad * 4 + r;
            bh4 pk;
#pragma unroll
            for (int sub = 0; sub < 4; ++sub)
              pk[sub] = (__bf16)__builtin_amdgcn_exp2f(sac[sub][r]);
            *(bh4*)(Pw[fr] + prow * 64 + ((lm >> 1) ^ (prow & 7)) * 8 + (lm & 1) * 4) = pk;
          }
        }
      }
    }
    __asm__ volatile("s_waitcnt lgkmcnt(0)" ::: "memory");
    bfrag vf[8];
#pragma unroll
    for (int sub = 0; sub < 4; ++sub)
#pragma unroll
      for (int f = 0; f < 2; ++f)
        vf[sub * 2 + f] = *(const bfrag*)(Vs + (sub * 16 + lm) * 64 + ((f * 4 + quad) ^ rsw) * 8);
#pragma unroll
    for (int fr = 0; fr < 4; ++fr) {
      if (kBase <= row0[fr] + 15) {
#pragma unroll
        for (int f = 0; f < 2; ++f) {
          bfrag pf = *(const bfrag*)(Pw[fr] + lm * 64 + ((f * 4 + quad) ^ rsw) * 8);
          L[fr] = __builtin_amdgcn_mfma_f32_16x16x32_bf16(pf, ones, L[fr], 0, 0, 0);
#pragma unroll
          for (int ds = 0; ds < 4; ++ds)
            y[fr][ds] = __builtin_amdgcn_mfma_f32_16x16x32_bf16(pf, vf[ds * 2 + f], y[fr][ds], 0, 0, 0);
        }
      }
    }
    if (more) {
      kin[0] = kin2[0]; kin[1] = kin2[1];
      vin[0] = vin2[0]; vin[1] = vin2[1];
    }
  }
#pragma unroll
  for (int fr = 0; fr < 4; ++fr)
#pragma unroll
    for (int ds = 0; ds < 4; ++ds)
#pragma unroll
      for (int r = 0; r < 4; ++r) {
        long row = rbase + row0[fr] + quad * 4 + r;
        Yg[row * CC + hoff + ds * 16 + lm] = (__bf16)(y[fr][ds][r] / L[fr][r]);
      }
}

extern "C" void kernel_launch(void* const* d_in, const int* in_sizes, int n_in,
                              void* d_out, int out_size, void* d_ws, size_t ws_size,
                              hipStream_t stream) {
  (void)in_sizes; (void)n_in; (void)out_size;
  const float* x  = (const float*)d_in[0];
  const float* Wq = (const float*)d_in[1];
  const float* Wk = (const float*)d_in[2];
  const float* Wv = (const float*)d_in[3];
  const float* Wp = (const float*)d_in[4];
  float* out = (float*)d_out;
  const long R = 8192;             // B*T
  const long BUF = R * 1024;
  const long WN = 1024L * 1024;
  __bf16* qb = (__bf16*)d_ws;      // q (pre-scaled), then y in-place
  __bf16* kb = (__bf16*)d_out;     // k + vt borrow d_out (dead before final GEMM)
  __bf16* vslot = kb + BUF;
  dim3 blk(256, 1, 1);
  const size_t need = (size_t)(2 * BUF + 4 * WN) * 2;
  if (ws_size >= need) {
    __bf16* xb = qb + BUF;
    __bf16* wqkv = xb + BUF;       // Wq,Wk,Wv contiguous = [3072][1024]
    __bf16* wpb = wqkv + 3 * WN;
    cvt5<<<dim3((unsigned)(BUF / (256 * 8)), 5, 1), blk, 0, stream>>>(
        x, Wq, Wk, Wv, Wp, xb, wqkv, wqkv + WN, wqkv + 2 * WN, wpb, BUF, WN);
    gemm_dp<0><<<dim3(64, 12, 1), dim3(512, 1, 1), 0, stream>>>(
        xb, wqkv, qb, kb, vslot, nullptr, 1024);
    attn_fwd10<true><<<dim3(64, 8, 1), blk, 0, stream>>>(qb, kb, vslot, qb);
    gemm_dp<1><<<dim3(64, 4, 1), dim3(512, 1, 1), 0, stream>>>(
        qb, wpb, nullptr, nullptr, nullptr, out, 1024);
  } else {
    gemm_bt_cv<true, false><<<dim3(64, 8, 1), blk, 0, stream>>>(x, Wq, qb, 8192, 1024, 1024, QSCALE);
    gemm_bt_cv<true, false><<<dim3(64, 8, 1), blk, 0, stream>>>(x, Wk, kb, 8192, 1024, 1024, 1.0f);
    gemm_bt_cv<true, false><<<dim3(64, 8, 1), blk, 0, stream>>>(x, Wv, vslot, 8192, 1024, 1024, 1.0f);
    attn_fwd10<false><<<dim3(64, 8, 1), blk, 0, stream>>>(qb, kb, vslot, qb);
    gemm_bt_cv<false, true><<<dim3(64, 8, 1), blk, 0, stream>>>(qb, Wp, out, 8192, 1024, 1024, 1.0f);
  }
}